// Round 15
// baseline (1891.047 us; speedup 1.0000x reference)
//
#include <hip/hip_runtime.h>
#include <math.h>

#define NN 1024
#define FF 128
#define DD 256
#define HH 8
#define CC 32
#define EE 32768
#define NEDGE (EE + NN)

typedef float f32x4 __attribute__((ext_vector_type(4)));

// fast gates for the recurrence critical path (graceful at +-inf, no NaN)
__device__ __forceinline__ float fsig(float x) { return 1.0f / (1.0f + __expf(-x)); }
__device__ __forceinline__ float ftanh(float x) { return 2.0f / (1.0f + __expf(-2.0f * x)) - 1.0f; }

// barrier that only guarantees LDS visibility (no vmcnt drain: global publishes
// stay in flight; parity-ring data dependency orders slot reuse, not the barrier)
__device__ __forceinline__ void barrier_lds() {
  asm volatile("s_waitcnt lgkmcnt(0)" ::: "memory");
  __builtin_amdgcn_sched_barrier(0);
  __builtin_amdgcn_s_barrier();
}

// ---------------- CSR build (dst-indexed) ----------------
__global__ void k_count(const int* __restrict__ ei, int* __restrict__ count) {
  int k = blockIdx.x * blockDim.x + threadIdx.x;
  if (k >= NEDGE) return;
  int d = (k < EE) ? ei[EE + k] : (k - EE);
  atomicAdd(&count[d], 1);
}

__global__ void k_scan(const int* __restrict__ count, int* __restrict__ rowptr, int* __restrict__ cursor) {
  __shared__ int buf[NN];
  int t = threadIdx.x;
  int c = count[t];
  buf[t] = c;
  __syncthreads();
  for (int off = 1; off < NN; off <<= 1) {
    int add = (t >= off) ? buf[t - off] : 0;
    __syncthreads();
    buf[t] += add;
    __syncthreads();
  }
  int inc = buf[t];
  rowptr[t] = inc - c;
  cursor[t] = inc - c;
  if (t == NN - 1) rowptr[NN] = inc;
}

__global__ void k_scatter(const int* __restrict__ ei, int* __restrict__ cursor, int* __restrict__ csrc) {
  int k = blockIdx.x * blockDim.x + threadIdx.x;
  if (k >= NEDGE) return;
  int s, d;
  if (k < EE) { s = ei[k]; d = ei[EE + k]; }
  else        { s = k - EE; d = k - EE; }
  int pos = atomicAdd(&cursor[d], 1);
  csrc[pos] = s;
}

// ---------------- fp32 GEMM: C = A@B (or A@B^T) [+bias1+bias2] ----------------
template<bool BT, bool ADDB>
__global__ __launch_bounds__(256) void k_gemm(const float* __restrict__ A, const float* __restrict__ B,
    const float* __restrict__ bias1, const float* __restrict__ bias2, float* __restrict__ C,
    int M, int N, int K) {
  __shared__ float At[64][17];
  __shared__ float Bt[16][65];
  const int tid = threadIdx.x;
  const int m0 = blockIdx.x * 64, n0 = blockIdx.y * 64;
  const int tx = tid & 15, ty = tid >> 4;
  float acc[4][4] = {{0.f, 0.f, 0.f, 0.f}};
  for (int k0 = 0; k0 < K; k0 += 16) {
    {
      int rr = tid >> 2, kl = (tid & 3) * 4;
      float4 a = *(const float4*)(A + (m0 + rr) * K + k0 + kl);
      At[rr][kl] = a.x; At[rr][kl + 1] = a.y; At[rr][kl + 2] = a.z; At[rr][kl + 3] = a.w;
    }
    if (BT) {
      int nn = tid >> 2, kl = (tid & 3) * 4;
      float4 b = *(const float4*)(B + (n0 + nn) * K + k0 + kl);
      Bt[kl][nn] = b.x; Bt[kl + 1][nn] = b.y; Bt[kl + 2][nn] = b.z; Bt[kl + 3][nn] = b.w;
    } else {
      int kk = tid >> 4, nn = (tid & 15) * 4;
      float4 b = *(const float4*)(B + (k0 + kk) * N + n0 + nn);
      Bt[kk][nn] = b.x; Bt[kk][nn + 1] = b.y; Bt[kk][nn + 2] = b.z; Bt[kk][nn + 3] = b.w;
    }
    __syncthreads();
    #pragma unroll
    for (int kk = 0; kk < 16; ++kk) {
      float av[4], bv[4];
      #pragma unroll
      for (int i = 0; i < 4; ++i) av[i] = At[ty * 4 + i][kk];
      #pragma unroll
      for (int jj = 0; jj < 4; ++jj) bv[jj] = Bt[kk][tx * 4 + jj];
      #pragma unroll
      for (int i = 0; i < 4; ++i)
        #pragma unroll
        for (int jj = 0; jj < 4; ++jj)
          acc[i][jj] = fmaf(av[i], bv[jj], acc[i][jj]);
    }
    __syncthreads();
  }
  #pragma unroll
  for (int i = 0; i < 4; ++i) {
    #pragma unroll
    for (int jj = 0; jj < 4; ++jj) {
      int n = n0 + tx * 4 + jj;
      float v = acc[i][jj];
      if (ADDB) v += bias1[n] + bias2[n];
      C[(m0 + ty * 4 + i) * N + n] = v;
    }
  }
}

// ---------------- per-node attention scores es/ed ----------------
__global__ __launch_bounds__(256) void k_att(const float* __restrict__ h, const float* __restrict__ asrc,
    const float* __restrict__ adst, float* __restrict__ es, float* __restrict__ ed) {
  int n = blockIdx.x;
  int hd = threadIdx.x >> 5, c = threadIdx.x & 31;
  float hv = h[n * DD + hd * CC + c];
  float e1 = hv * asrc[hd * CC + c];
  float e2 = hv * adst[hd * CC + c];
  #pragma unroll
  for (int msk = 1; msk < 32; msk <<= 1) { e1 += __shfl_xor(e1, msk); e2 += __shfl_xor(e2, msk); }
  if (c == 0) { es[n * HH + hd] = e1; ed[n * HH + hd] = e2; }
}

// ---------------- per-(dst,head) softmax + aggregate (+bias, relu) ----------------
__global__ __launch_bounds__(256) void k_agg(const float* __restrict__ h, const float* __restrict__ es,
    const float* __restrict__ ed, const float* __restrict__ bias, const int* __restrict__ rowptr,
    const int* __restrict__ csrc, float* __restrict__ out) {
  int w = blockIdx.x * 4 + (threadIdx.x >> 6);
  int lane = threadIdx.x & 63;
  int n = w >> 3, hd = w & 7;
  int lo = rowptr[n], hi = rowptr[n + 1];
  float edn = ed[n * HH + hd];
  float m = -1e30f;
  for (int k = lo + lane; k < hi; k += 64) {
    int s = csrc[k];
    float e = es[s * HH + hd] + edn;
    e = (e > 0.f) ? e : 0.2f * e;
    m = fmaxf(m, e);
  }
  #pragma unroll
  for (int msk = 1; msk < 64; msk <<= 1) m = fmaxf(m, __shfl_xor(m, msk));
  float den = 0.f;
  for (int k = lo + lane; k < hi; k += 64) {
    int s = csrc[k];
    float e = es[s * HH + hd] + edn;
    e = (e > 0.f) ? e : 0.2f * e;
    den += expf(e - m);
  }
  #pragma unroll
  for (int msk = 1; msk < 64; msk <<= 1) den += __shfl_xor(den, msk);
  float inv = 1.0f / (den + 1e-16f);
  int c = lane & 31, halfsel = lane >> 5;
  float acc = 0.f;
  for (int k = lo + halfsel; k < hi; k += 2) {
    int s = csrc[k];
    float e = es[s * HH + hd] + edn;
    e = (e > 0.f) ? e : 0.2f * e;
    float al = expf(e - m) * inv;
    acc += al * h[s * DD + hd * CC + c];
  }
  acc += __shfl_down(acc, 32);
  if (lane < 32) {
    float v = acc + bias[hd * CC + c];
    out[n * DD + hd * CC + c] = fmaxf(v, 0.f);
  }
}

// ---------------- LSTM recurrence: 8 blocks, private-mailbox LLC handshake ----------------
// Block j owns h-cols [j*32, j*32+32). Publish: self-tagged u64 ((h_bits<<32)|step),
// written to each consumer's PRIVATE mailbox region (1 writer + 1 reading block per
// line — kills the all-to-all line contention of rounds 6-10). Full wave 0 is the
// publisher: lanes 0-31 compute gates + 3 peer stores + LDS/hs; lanes 32-63
// recompute gates redundantly (same zlds => identical) + 4 peer stores. Pollers
// (t in [64,288)) each own ONE mailbox word. CRITICAL: publishers and pollers are
// in DIFFERENT waves — rounds 12-14 proved the same-wave layout deadlocks at s=0
// (exec-masked region ordering lets polls run before the wave's own publishes
// drain). Parity double-buffer; ring invariant bounds producers to 1 publish
// ahead (proven rounds 2-11). Whh in VGPRs via keep-alive asm (opaque def => no
// remat/sink). Rotated LDS reads (0 bank conflicts). lgkmcnt-only barriers.
// Persistent spin budget => always terminates.
__global__ __launch_bounds__(512, 1) void k_lstm(const float* __restrict__ xW,
    const float* __restrict__ Whh, unsigned long long* __restrict__ mbox,
    float* __restrict__ hs) {
  const int j = blockIdx.x;
  const int t = threadIdx.x;
  const int r = t >> 2, qt = t & 3;            // row 0..127, quarter 0..3
  const int g = r >> 5, kl = r & 31;
  const int grow = g * 256 + j * 32 + kl;      // z-row in [0,1024)
  __shared__ float hlds[DD];
  __shared__ float zlds[128];

  // Whh quarter-slice in VGPRs (rotated order, matching dot-phase reads).
  // keep-alive asm makes each w[q] an opaque asm-defined value: the allocator
  // cannot rematerialize it from memory (the round-6 spill/sink failure mode).
  f32x4 w[16];
  {
    const f32x4* W4 = (const f32x4*)(Whh + grow * DD + qt * 64);
    #pragma unroll
    for (int q = 0; q < 16; ++q) w[q] = W4[(q + 4 * qt) & 15];
    #pragma unroll
    for (int q = 0; q < 16; ++q) asm volatile("" : "+v"(w[q]));
  }
  if (t < DD) hlds[t] = 0.f;
  float creg = 0.f;
  float xwv = (qt == 0) ? xW[grow] : 0.f;
  int bud = 1 << 22;  // persistent spin budget: hang-proof
  __syncthreads();

  for (int s = 0; s < NN; ++s) {
    // ---- dot: quarter-partial of z[grow]; rotated reads => conflict-free ----
    const f32x4* h4 = (const f32x4*)hlds + qt * 16;
    float ac4[4] = {0.f, 0.f, 0.f, 0.f};
    #pragma unroll
    for (int q = 0; q < 16; ++q) {
      f32x4 hv = h4[(q + 4 * qt) & 15];
      f32x4 wv = w[q];
      ac4[q & 3] = fmaf(wv.x, hv.x, ac4[q & 3]);
      ac4[q & 3] = fmaf(wv.y, hv.y, ac4[q & 3]);
      ac4[q & 3] = fmaf(wv.z, hv.z, ac4[q & 3]);
      ac4[q & 3] = fmaf(wv.w, hv.w, ac4[q & 3]);
    }
    float acc = (ac4[0] + ac4[1]) + (ac4[2] + ac4[3]);
    acc += __shfl_xor(acc, 1);
    acc += __shfl_xor(acc, 2);
    if (qt == 0) zlds[r] = acc + xwv;
    barrier_lds();

    const int par = (s + 1) & 1;
    const unsigned int tag = (unsigned int)(s + 1);
    // prefetch next step's xW early (qt==0 lanes only)
    float xw_next = (qt == 0 && s + 1 < NN) ? xW[(s + 1) * 1024 + grow] : 0.f;

    if (t < 64) {
      // ---- publisher wave: both halves compute gates (identical inputs) ----
      int lane = t & 31;
      float iv = zlds[lane], fv = zlds[32 + lane], gv = zlds[64 + lane], ov = zlds[96 + lane];
      creg = fsig(fv) * creg + fsig(iv) * ftanh(gv);
      float hn = fsig(ov) * ftanh(creg);
      int col = j * 32 + lane;
      unsigned long long pk = ((unsigned long long)__float_as_uint(hn) << 32) | tag;
      if (t < 32) {
        // peers at offsets 1..3, then local LDS + hs
        #pragma unroll
        for (int po = 1; po <= 3; ++po) {
          int p = j + po; if (p >= 8) p -= 8;
          __hip_atomic_store(&mbox[(p * 2 + par) * DD + col], pk,
                             __ATOMIC_RELAXED, __HIP_MEMORY_SCOPE_AGENT);
        }
        hlds[col] = hn;
        hs[s * DD + col] = hn;
      } else {
        // peers at offsets 4..7
        #pragma unroll
        for (int po = 4; po <= 7; ++po) {
          int p = j + po; if (p >= 8) p -= 8;
          __hip_atomic_store(&mbox[(p * 2 + par) * DD + col], pk,
                             __ATOMIC_RELAXED, __HIP_MEMORY_SCOPE_AGENT);
        }
      }
    } else if (t < 288) {
      // ---- pollers: 224 threads, each owns ONE private mailbox word ----
      int pi = t - 64;
      int peer = j + 1 + (pi >> 5); if (peer >= 8) peer -= 8;
      int col = peer * 32 + (pi & 31);
      unsigned long long* wp = &mbox[(j * 2 + par) * DD + col];
      unsigned long long a;
      for (;;) {
        a = __hip_atomic_load(wp, __ATOMIC_RELAXED, __HIP_MEMORY_SCOPE_AGENT);
        if ((unsigned int)(a & 0xffffffffULL) == tag) break;
        if (--bud <= 0) break;
      }
      hlds[col] = __uint_as_float((unsigned int)(a >> 32));
    }
    barrier_lds();
    xwv = xw_next;
  }
}

// ---------------- final per-edge outputs ----------------
__global__ __launch_bounds__(256) void k_edges(const float* __restrict__ hs, const int* __restrict__ ei,
    const float* __restrict__ Wp, const float* __restrict__ bp,
    const float* __restrict__ Wc, const float* __restrict__ bc, float* __restrict__ out) {
  int widx = threadIdx.x >> 6, lane = threadIdx.x & 63;
  int k = blockIdx.x * 4 + widx;
  int sIdx = ei[k], dIdx = ei[EE + k];
  float4 u = ((const float4*)(hs + sIdx * DD))[lane];
  float4 v = ((const float4*)(hs + dIdx * DD))[lane];
  float4 wp = ((const float4*)Wp)[lane];
  float4 wc = ((const float4*)Wc)[lane];
  float x0 = u.x * v.x, x1 = u.y * v.y, x2 = u.z * v.z, x3 = u.w * v.w;
  float ap = x0 * wp.x + x1 * wp.y + x2 * wp.z + x3 * wp.w;
  float ac = x0 * wc.x + x1 * wc.y + x2 * wc.z + x3 * wc.w;
  #pragma unroll
  for (int msk = 1; msk < 64; msk <<= 1) { ap += __shfl_xor(ap, msk); ac += __shfl_xor(ac, msk); }
  if (lane == 0) { out[k] = ap + bp[0]; out[EE + k] = ac + bc[0]; }
}

extern "C" void kernel_launch(void* const* d_in, const int* in_sizes, int n_in,
                              void* d_out, int out_size, void* d_ws, size_t ws_size,
                              hipStream_t stream) {
  const float* x       = (const float*)d_in[0];
  const int* ei        = (const int*)d_in[1];
  const float* W1      = (const float*)d_in[3];
  const float* as1     = (const float*)d_in[4];
  const float* ad1     = (const float*)d_in[5];
  const float* b1      = (const float*)d_in[6];
  const float* W2      = (const float*)d_in[7];
  const float* as2     = (const float*)d_in[8];
  const float* ad2     = (const float*)d_in[9];
  const float* b2      = (const float*)d_in[10];
  const float* Wih     = (const float*)d_in[11];
  const float* Whh     = (const float*)d_in[12];
  const float* bih     = (const float*)d_in[13];
  const float* bhh     = (const float*)d_in[14];
  const float* Wp      = (const float*)d_in[15];
  const float* bp      = (const float*)d_in[16];
  const float* Wc      = (const float*)d_in[17];
  const float* bc      = (const float*)d_in[18];
  float* out = (float*)d_out;

  char* ws = (char*)d_ws;
  int* counts                = (int*)(ws + 0);        // 4 KB  [memset]
  unsigned long long* mbox   = (unsigned long long*)(ws + 4096);  // 32 KB [memset] 8 consumers x 2 x 256
  int* rowptr                = (int*)(ws + 36864);    // 8 KB
  int* cursor                = (int*)(ws + 45056);    // 4 KB
  int* csrc                  = (int*)(ws + 49152);    // 136 KB
  float* es                  = (float*)(ws + 188416); // 32 KB
  float* ed                  = (float*)(ws + 221184); // 32 KB
  float* buf0                = (float*)(ws + 253952); // 1 MB
  float* buf1                = (float*)(ws + 1302528);// 1 MB
  float* xW                  = (float*)(ws + 2351104);// 4 MB
  float* hsall               = (float*)(ws + 6545408);// 1 MB

  // zero counts + mailboxes (in-graph => reset on every replay)
  hipMemsetAsync(ws, 0, 36864, stream);

  // CSR by dst (E edges + N self-loops)
  k_count  <<<(NEDGE + 255) / 256, 256, 0, stream>>>(ei, counts);
  k_scan   <<<1, 1024, 0, stream>>>(counts, rowptr, cursor);
  k_scatter<<<(NEDGE + 255) / 256, 256, 0, stream>>>(ei, cursor, csrc);

  // GAT layer 1 (graph (0,0) only)
  k_gemm<false, false><<<dim3(16, 4), 256, 0, stream>>>(x, W1, nullptr, nullptr, buf0, NN, DD, FF);
  k_att<<<NN, 256, 0, stream>>>(buf0, as1, ad1, es, ed);
  k_agg<<<NN * HH / 4, 256, 0, stream>>>(buf0, es, ed, b1, rowptr, csrc, buf1);

  // GAT layer 2
  k_gemm<false, false><<<dim3(16, 4), 256, 0, stream>>>(buf1, W2, nullptr, nullptr, buf0, NN, DD, DD);
  k_att<<<NN, 256, 0, stream>>>(buf0, as2, ad2, es, ed);
  k_agg<<<NN * HH / 4, 256, 0, stream>>>(buf0, es, ed, b2, rowptr, csrc, buf1);

  // LSTM input projection: xW[n, j] = h2[n,:]·Wih[j,:] + bih[j] + bhh[j]
  k_gemm<true, true><<<dim3(16, 16), 256, 0, stream>>>(buf1, Wih, bih, bhh, xW, NN, 1024, DD);

  // sequential recurrence: 8 blocks, private-mailbox handshake
  k_lstm<<<8, 512, 0, stream>>>(xW, Whh, mbox, hsall);

  // final per-edge predictions
  k_edges<<<EE / 4, 256, 0, stream>>>(hsall, ei, Wp, bp, Wc, bc, out);
}

// Round 16
// 1856.826 us; speedup vs baseline: 1.0184x; 1.0184x over previous
//
#include <hip/hip_runtime.h>
#include <math.h>

#define NN 1024
#define FF 128
#define DD 256
#define HH 8
#define CC 32
#define EE 32768
#define NEDGE (EE + NN)

typedef float f32x4 __attribute__((ext_vector_type(4)));

// fast gates for the recurrence critical path (graceful at +-inf, no NaN)
__device__ __forceinline__ float fsig(float x) { return 1.0f / (1.0f + __expf(-x)); }
__device__ __forceinline__ float ftanh(float x) { return 2.0f / (1.0f + __expf(-2.0f * x)) - 1.0f; }

// barrier that only guarantees LDS visibility (no vmcnt drain: global publishes
// stay in flight; parity-ring data dependency orders slot reuse, not the barrier)
__device__ __forceinline__ void barrier_lds() {
  asm volatile("s_waitcnt lgkmcnt(0)" ::: "memory");
  __builtin_amdgcn_sched_barrier(0);
  __builtin_amdgcn_s_barrier();
}

// ---------------- CSR build (dst-indexed) ----------------
__global__ void k_count(const int* __restrict__ ei, int* __restrict__ count) {
  int k = blockIdx.x * blockDim.x + threadIdx.x;
  if (k >= NEDGE) return;
  int d = (k < EE) ? ei[EE + k] : (k - EE);
  atomicAdd(&count[d], 1);
}

__global__ void k_scan(const int* __restrict__ count, int* __restrict__ rowptr, int* __restrict__ cursor) {
  __shared__ int buf[NN];
  int t = threadIdx.x;
  int c = count[t];
  buf[t] = c;
  __syncthreads();
  for (int off = 1; off < NN; off <<= 1) {
    int add = (t >= off) ? buf[t - off] : 0;
    __syncthreads();
    buf[t] += add;
    __syncthreads();
  }
  int inc = buf[t];
  rowptr[t] = inc - c;
  cursor[t] = inc - c;
  if (t == NN - 1) rowptr[NN] = inc;
}

__global__ void k_scatter(const int* __restrict__ ei, int* __restrict__ cursor, int* __restrict__ csrc) {
  int k = blockIdx.x * blockDim.x + threadIdx.x;
  if (k >= NEDGE) return;
  int s, d;
  if (k < EE) { s = ei[k]; d = ei[EE + k]; }
  else        { s = k - EE; d = k - EE; }
  int pos = atomicAdd(&cursor[d], 1);
  csrc[pos] = s;
}

// ---------------- fp32 GEMM: C = A@B (or A@B^T) [+bias1+bias2] ----------------
template<bool BT, bool ADDB>
__global__ __launch_bounds__(256) void k_gemm(const float* __restrict__ A, const float* __restrict__ B,
    const float* __restrict__ bias1, const float* __restrict__ bias2, float* __restrict__ C,
    int M, int N, int K) {
  __shared__ float At[64][17];
  __shared__ float Bt[16][65];
  const int tid = threadIdx.x;
  const int m0 = blockIdx.x * 64, n0 = blockIdx.y * 64;
  const int tx = tid & 15, ty = tid >> 4;
  float acc[4][4] = {{0.f, 0.f, 0.f, 0.f}};
  for (int k0 = 0; k0 < K; k0 += 16) {
    {
      int rr = tid >> 2, kl = (tid & 3) * 4;
      float4 a = *(const float4*)(A + (m0 + rr) * K + k0 + kl);
      At[rr][kl] = a.x; At[rr][kl + 1] = a.y; At[rr][kl + 2] = a.z; At[rr][kl + 3] = a.w;
    }
    if (BT) {
      int nn = tid >> 2, kl = (tid & 3) * 4;
      float4 b = *(const float4*)(B + (n0 + nn) * K + k0 + kl);
      Bt[kl][nn] = b.x; Bt[kl + 1][nn] = b.y; Bt[kl + 2][nn] = b.z; Bt[kl + 3][nn] = b.w;
    } else {
      int kk = tid >> 4, nn = (tid & 15) * 4;
      float4 b = *(const float4*)(B + (k0 + kk) * N + n0 + nn);
      Bt[kk][nn] = b.x; Bt[kk][nn + 1] = b.y; Bt[kk][nn + 2] = b.z; Bt[kk][nn + 3] = b.w;
    }
    __syncthreads();
    #pragma unroll
    for (int kk = 0; kk < 16; ++kk) {
      float av[4], bv[4];
      #pragma unroll
      for (int i = 0; i < 4; ++i) av[i] = At[ty * 4 + i][kk];
      #pragma unroll
      for (int jj = 0; jj < 4; ++jj) bv[jj] = Bt[kk][tx * 4 + jj];
      #pragma unroll
      for (int i = 0; i < 4; ++i)
        #pragma unroll
        for (int jj = 0; jj < 4; ++jj)
          acc[i][jj] = fmaf(av[i], bv[jj], acc[i][jj]);
    }
    __syncthreads();
  }
  #pragma unroll
  for (int i = 0; i < 4; ++i) {
    #pragma unroll
    for (int jj = 0; jj < 4; ++jj) {
      int n = n0 + tx * 4 + jj;
      float v = acc[i][jj];
      if (ADDB) v += bias1[n] + bias2[n];
      C[(m0 + ty * 4 + i) * N + n] = v;
    }
  }
}

// ---------------- per-node attention scores es/ed ----------------
__global__ __launch_bounds__(256) void k_att(const float* __restrict__ h, const float* __restrict__ asrc,
    const float* __restrict__ adst, float* __restrict__ es, float* __restrict__ ed) {
  int n = blockIdx.x;
  int hd = threadIdx.x >> 5, c = threadIdx.x & 31;
  float hv = h[n * DD + hd * CC + c];
  float e1 = hv * asrc[hd * CC + c];
  float e2 = hv * adst[hd * CC + c];
  #pragma unroll
  for (int msk = 1; msk < 32; msk <<= 1) { e1 += __shfl_xor(e1, msk); e2 += __shfl_xor(e2, msk); }
  if (c == 0) { es[n * HH + hd] = e1; ed[n * HH + hd] = e2; }
}

// ---------------- per-(dst,head) softmax + aggregate (+bias, relu) ----------------
__global__ __launch_bounds__(256) void k_agg(const float* __restrict__ h, const float* __restrict__ es,
    const float* __restrict__ ed, const float* __restrict__ bias, const int* __restrict__ rowptr,
    const int* __restrict__ csrc, float* __restrict__ out) {
  int w = blockIdx.x * 4 + (threadIdx.x >> 6);
  int lane = threadIdx.x & 63;
  int n = w >> 3, hd = w & 7;
  int lo = rowptr[n], hi = rowptr[n + 1];
  float edn = ed[n * HH + hd];
  float m = -1e30f;
  for (int k = lo + lane; k < hi; k += 64) {
    int s = csrc[k];
    float e = es[s * HH + hd] + edn;
    e = (e > 0.f) ? e : 0.2f * e;
    m = fmaxf(m, e);
  }
  #pragma unroll
  for (int msk = 1; msk < 64; msk <<= 1) m = fmaxf(m, __shfl_xor(m, msk));
  float den = 0.f;
  for (int k = lo + lane; k < hi; k += 64) {
    int s = csrc[k];
    float e = es[s * HH + hd] + edn;
    e = (e > 0.f) ? e : 0.2f * e;
    den += expf(e - m);
  }
  #pragma unroll
  for (int msk = 1; msk < 64; msk <<= 1) den += __shfl_xor(den, msk);
  float inv = 1.0f / (den + 1e-16f);
  int c = lane & 31, halfsel = lane >> 5;
  float acc = 0.f;
  for (int k = lo + halfsel; k < hi; k += 2) {
    int s = csrc[k];
    float e = es[s * HH + hd] + edn;
    e = (e > 0.f) ? e : 0.2f * e;
    float al = expf(e - m) * inv;
    acc += al * h[s * DD + hd * CC + c];
  }
  acc += __shfl_down(acc, 32);
  if (lane < 32) {
    float v = acc + bias[hd * CC + c];
    out[n * DD + hd * CC + c] = fmaxf(v, 0.f);
  }
}

// ---------------- LSTM recurrence: 8 blocks, private-mailbox handshake ----------------
// IDENTICAL structure to the round-11/15 passing kernel (separate publisher and
// poller WAVES — same-wave layout proven broken in rounds 12-14), with ONE delta:
// pollers sample via a self-contained asm 3-deep staggered load rotation using
// BOTH sc0 AND sc1 (matching the atomic path: sc1 bypasses non-coherent L2,
// sc0 bypasses L1 — round 13's sc1-only loads polled a stale L1 line forever).
// Sampling period drops ~RT -> ~RT/3. Wave-uniform exits; vmcnt(0) drain on every
// exit; small budget + warm-up-aware demotion + proven C atomic fallback =>
// correct and hang-proof under any cache behavior (downside ~= round-15 speed).
__global__ __launch_bounds__(512, 1) void k_lstm(const float* __restrict__ xW,
    const float* __restrict__ Whh, unsigned long long* __restrict__ mbox,
    float* __restrict__ hs) {
  const int j = blockIdx.x;
  const int t = threadIdx.x;
  const int r = t >> 2, qt = t & 3;            // row 0..127, quarter 0..3
  const int g = r >> 5, kl = r & 31;
  const int grow = g * 256 + j * 32 + kl;      // z-row in [0,1024)
  __shared__ float hlds[DD];
  __shared__ float zlds[128];

  // Whh quarter-slice in VGPRs (rotated order, matching dot-phase reads).
  // keep-alive asm makes each w[q] an opaque asm-defined value: the allocator
  // cannot rematerialize it from memory (the round-6 spill/sink failure mode).
  f32x4 w[16];
  {
    const f32x4* W4 = (const f32x4*)(Whh + grow * DD + qt * 64);
    #pragma unroll
    for (int q = 0; q < 16; ++q) w[q] = W4[(q + 4 * qt) & 15];
    #pragma unroll
    for (int q = 0; q < 16; ++q) asm volatile("" : "+v"(w[q]));
  }
  if (t < DD) hlds[t] = 0.f;
  float creg = 0.f;
  float xwv = (qt == 0) ? xW[grow] : 0.f;
  int bud = 1 << 22;          // persistent C fallback budget: hang-proof
  int lateMiss = 0;
  unsigned int abud = 64;     // asm poll budget (rotations); demoted if useless
  __syncthreads();

  for (int s = 0; s < NN; ++s) {
    // ---- dot: quarter-partial of z[grow]; rotated reads => conflict-free ----
    const f32x4* h4 = (const f32x4*)hlds + qt * 16;
    float ac4[4] = {0.f, 0.f, 0.f, 0.f};
    #pragma unroll
    for (int q = 0; q < 16; ++q) {
      f32x4 hv = h4[(q + 4 * qt) & 15];
      f32x4 wv = w[q];
      ac4[q & 3] = fmaf(wv.x, hv.x, ac4[q & 3]);
      ac4[q & 3] = fmaf(wv.y, hv.y, ac4[q & 3]);
      ac4[q & 3] = fmaf(wv.z, hv.z, ac4[q & 3]);
      ac4[q & 3] = fmaf(wv.w, hv.w, ac4[q & 3]);
    }
    float acc = (ac4[0] + ac4[1]) + (ac4[2] + ac4[3]);
    acc += __shfl_xor(acc, 1);
    acc += __shfl_xor(acc, 2);
    if (qt == 0) zlds[r] = acc + xwv;
    barrier_lds();

    const int par = (s + 1) & 1;
    const unsigned int tag = (unsigned int)(s + 1);
    // prefetch next step's xW early (qt==0 lanes only)
    float xw_next = (qt == 0 && s + 1 < NN) ? xW[(s + 1) * 1024 + grow] : 0.f;

    if (t < 64) {
      // ---- publisher wave: both halves compute gates (identical inputs) ----
      int lane = t & 31;
      float iv = zlds[lane], fv = zlds[32 + lane], gv = zlds[64 + lane], ov = zlds[96 + lane];
      creg = fsig(fv) * creg + fsig(iv) * ftanh(gv);
      float hn = fsig(ov) * ftanh(creg);
      int col = j * 32 + lane;
      unsigned long long pk = ((unsigned long long)__float_as_uint(hn) << 32) | tag;
      if (t < 32) {
        #pragma unroll
        for (int po = 1; po <= 3; ++po) {
          int p = j + po; if (p >= 8) p -= 8;
          __hip_atomic_store(&mbox[(p * 2 + par) * DD + col], pk,
                             __ATOMIC_RELAXED, __HIP_MEMORY_SCOPE_AGENT);
        }
        hlds[col] = hn;
        hs[s * DD + col] = hn;
      } else {
        #pragma unroll
        for (int po = 4; po <= 7; ++po) {
          int p = j + po; if (p >= 8) p -= 8;
          __hip_atomic_store(&mbox[(p * 2 + par) * DD + col], pk,
                             __ATOMIC_RELAXED, __HIP_MEMORY_SCOPE_AGENT);
        }
      }
    } else if (t < 288) {
      // ---- pollers (separate waves): 224 threads, one private mailbox word ----
      int pi = t - 64;
      int peer = j + 1 + (pi >> 5); if (peer >= 8) peer -= 8;
      int col = peer * 32 + (pi & 31);
      unsigned long long* wp = &mbox[(j * 2 + par) * DD + col];
      unsigned int bud_u = __builtin_amdgcn_readfirstlane(abud);
      unsigned int r0, r1;
      // 3-deep staggered sampling; sc0 sc1 = bypass L1 AND L2 (the atomic path).
      // Wave-uniform exits (vccz = all active lanes matched); every exit drains
      // vmcnt(0) so no load is left in flight targeting v50-v55.
      asm volatile(
        "s_mov_b32 s20, %[b]\n\t"
        "global_load_dwordx2 v[50:51], %[a], off sc0 sc1\n\t"
        "global_load_dwordx2 v[52:53], %[a], off sc0 sc1\n\t"
        "global_load_dwordx2 v[54:55], %[a], off sc0 sc1\n\t"
        "1:\n\t"
        "s_waitcnt vmcnt(2)\n\t"
        "v_cmp_ne_u32 vcc, %[t], v50\n\t"
        "s_cbranch_vccz 5f\n\t"
        "global_load_dwordx2 v[50:51], %[a], off sc0 sc1\n\t"
        "s_waitcnt vmcnt(2)\n\t"
        "v_cmp_ne_u32 vcc, %[t], v52\n\t"
        "s_cbranch_vccz 6f\n\t"
        "global_load_dwordx2 v[52:53], %[a], off sc0 sc1\n\t"
        "s_waitcnt vmcnt(2)\n\t"
        "v_cmp_ne_u32 vcc, %[t], v54\n\t"
        "s_cbranch_vccz 7f\n\t"
        "global_load_dwordx2 v[54:55], %[a], off sc0 sc1\n\t"
        "s_sub_u32 s20, s20, 1\n\t"
        "s_cmp_lg_u32 s20, 0\n\t"
        "s_cbranch_scc1 1b\n\t"
        "s_branch 5f\n\t"
        "6:\n\t"
        "s_waitcnt vmcnt(0)\n\t"
        "v_mov_b32 v50, v52\n\t"
        "v_mov_b32 v51, v53\n\t"
        "s_branch 8f\n\t"
        "7:\n\t"
        "s_waitcnt vmcnt(0)\n\t"
        "v_mov_b32 v50, v54\n\t"
        "v_mov_b32 v51, v55\n\t"
        "s_branch 8f\n\t"
        "5:\n\t"
        "s_waitcnt vmcnt(0)\n\t"
        "8:\n\t"
        "v_mov_b32 %[r0], v50\n\t"
        "v_mov_b32 %[r1], v51"
        : [r0] "=v"(r0), [r1] "=v"(r1)
        : [a] "v"(wp), [t] "v"(tag), [b] "s"(bud_u)
        : "memory", "vcc", "s20", "v50", "v51", "v52", "v53", "v54", "v55");
      float hvv = __uint_as_float(r1);
      if (r0 != tag) {
        // proven fallback: relaxed agent atomic poll (rounds 9/11/15)
        if (s >= 4) { if (++lateMiss >= 8 && abud > 2) abud = 2; }
        unsigned long long a;
        for (;;) {
          a = __hip_atomic_load(wp, __ATOMIC_RELAXED, __HIP_MEMORY_SCOPE_AGENT);
          if ((unsigned int)(a & 0xffffffffULL) == tag) break;
          if (--bud <= 0) break;
        }
        hvv = __uint_as_float((unsigned int)(a >> 32));
      }
      hlds[col] = hvv;
    }
    barrier_lds();
    xwv = xw_next;
  }
}

// ---------------- final per-edge outputs ----------------
__global__ __launch_bounds__(256) void k_edges(const float* __restrict__ hs, const int* __restrict__ ei,
    const float* __restrict__ Wp, const float* __restrict__ bp,
    const float* __restrict__ Wc, const float* __restrict__ bc, float* __restrict__ out) {
  int widx = threadIdx.x >> 6, lane = threadIdx.x & 63;
  int k = blockIdx.x * 4 + widx;
  int sIdx = ei[k], dIdx = ei[EE + k];
  float4 u = ((const float4*)(hs + sIdx * DD))[lane];
  float4 v = ((const float4*)(hs + dIdx * DD))[lane];
  float4 wp = ((const float4*)Wp)[lane];
  float4 wc = ((const float4*)Wc)[lane];
  float x0 = u.x * v.x, x1 = u.y * v.y, x2 = u.z * v.z, x3 = u.w * v.w;
  float ap = x0 * wp.x + x1 * wp.y + x2 * wp.z + x3 * wp.w;
  float ac = x0 * wc.x + x1 * wc.y + x2 * wc.z + x3 * wc.w;
  #pragma unroll
  for (int msk = 1; msk < 64; msk <<= 1) { ap += __shfl_xor(ap, msk); ac += __shfl_xor(ac, msk); }
  if (lane == 0) { out[k] = ap + bp[0]; out[EE + k] = ac + bc[0]; }
}

extern "C" void kernel_launch(void* const* d_in, const int* in_sizes, int n_in,
                              void* d_out, int out_size, void* d_ws, size_t ws_size,
                              hipStream_t stream) {
  const float* x       = (const float*)d_in[0];
  const int* ei        = (const int*)d_in[1];
  const float* W1      = (const float*)d_in[3];
  const float* as1     = (const float*)d_in[4];
  const float* ad1     = (const float*)d_in[5];
  const float* b1      = (const float*)d_in[6];
  const float* W2      = (const float*)d_in[7];
  const float* as2     = (const float*)d_in[8];
  const float* ad2     = (const float*)d_in[9];
  const float* b2      = (const float*)d_in[10];
  const float* Wih     = (const float*)d_in[11];
  const float* Whh     = (const float*)d_in[12];
  const float* bih     = (const float*)d_in[13];
  const float* bhh     = (const float*)d_in[14];
  const float* Wp      = (const float*)d_in[15];
  const float* bp      = (const float*)d_in[16];
  const float* Wc      = (const float*)d_in[17];
  const float* bc      = (const float*)d_in[18];
  float* out = (float*)d_out;

  char* ws = (char*)d_ws;
  int* counts                = (int*)(ws + 0);        // 4 KB  [memset]
  unsigned long long* mbox   = (unsigned long long*)(ws + 4096);  // 32 KB [memset]
  int* rowptr                = (int*)(ws + 36864);    // 8 KB
  int* cursor                = (int*)(ws + 45056);    // 4 KB
  int* csrc                  = (int*)(ws + 49152);    // 136 KB
  float* es                  = (float*)(ws + 188416); // 32 KB
  float* ed                  = (float*)(ws + 221184); // 32 KB
  float* buf0                = (float*)(ws + 253952); // 1 MB
  float* buf1                = (float*)(ws + 1302528);// 1 MB
  float* xW                  = (float*)(ws + 2351104);// 4 MB
  float* hsall               = (float*)(ws + 6545408);// 1 MB

  // zero counts + mailboxes (in-graph => reset on every replay)
  hipMemsetAsync(ws, 0, 36864, stream);

  // CSR by dst (E edges + N self-loops)
  k_count  <<<(NEDGE + 255) / 256, 256, 0, stream>>>(ei, counts);
  k_scan   <<<1, 1024, 0, stream>>>(counts, rowptr, cursor);
  k_scatter<<<(NEDGE + 255) / 256, 256, 0, stream>>>(ei, cursor, csrc);

  // GAT layer 1 (graph (0,0) only)
  k_gemm<false, false><<<dim3(16, 4), 256, 0, stream>>>(x, W1, nullptr, nullptr, buf0, NN, DD, FF);
  k_att<<<NN, 256, 0, stream>>>(buf0, as1, ad1, es, ed);
  k_agg<<<NN * HH / 4, 256, 0, stream>>>(buf0, es, ed, b1, rowptr, csrc, buf1);

  // GAT layer 2
  k_gemm<false, false><<<dim3(16, 4), 256, 0, stream>>>(buf1, W2, nullptr, nullptr, buf0, NN, DD, DD);
  k_att<<<NN, 256, 0, stream>>>(buf0, as2, ad2, es, ed);
  k_agg<<<NN * HH / 4, 256, 0, stream>>>(buf0, es, ed, b2, rowptr, csrc, buf1);

  // LSTM input projection: xW[n, j] = h2[n,:]·Wih[j,:] + bih[j] + bhh[j]
  k_gemm<true, true><<<dim3(16, 16), 256, 0, stream>>>(buf1, Wih, bih, bhh, xW, NN, 1024, DD);

  // sequential recurrence: 8 blocks, private mailboxes + 3-deep asm poll
  k_lstm<<<8, 512, 0, stream>>>(xW, Whh, mbox, hsall);

  // final per-edge predictions
  k_edges<<<EE / 4, 256, 0, stream>>>(hsall, ei, Wp, bp, Wc, bc, out);
}